// Round 2
// baseline (22.177 us; speedup 1.0000x reference)
//
#include <hip/hip_runtime.h>

// DKSTE scoring: score[b] = || h0*(s*t0 - d*a*t1) + h1*(d*t0 + s*a*t1) ||_2
// s=(sign(x)+sign(y))/2, d=(sign(x)-sign(y))/2, a=sign(alpha), per dim.
//
// Two-kernel structure:
//  K1: pack per-(relation,dim) signs into one byte (2 bits each for
//      sign(x)+1, sign(y)+1, sign(alpha)+1) -> 500 x 512 B = 256 KB in d_ws.
//      Replaces 6 KB/element of f32 relation+alpha reads with 0.5 KB/element.
//  K2: one 64-lane wave per batch element. Gathers head/tail rows (4 KB each,
//      float4-coalesced), decodes sign byte, FMA chain, wave shuffle-reduce.

__global__ __launch_bounds__(256) void pack_rel_kernel(
    const float* __restrict__ rel,     // (500, 512, 2)
    const float* __restrict__ alpha,   // (500, 512)
    unsigned char* __restrict__ packed,
    int nrel)
{
    const int r = blockIdx.x;
    if (r >= nrel) return;
    for (int d = threadIdx.x; d < 512; d += 256) {
        const float x = rel[(size_t)r * 1024 + d * 2];
        const float y = rel[(size_t)r * 1024 + d * 2 + 1];
        const float a = alpha[(size_t)r * 512 + d];
        const unsigned sx = (x > 0.f) ? 2u : ((x < 0.f) ? 0u : 1u);
        const unsigned sy = (y > 0.f) ? 2u : ((y < 0.f) ? 0u : 1u);
        const unsigned sa = (a > 0.f) ? 2u : ((a < 0.f) ? 0u : 1u);
        packed[(size_t)r * 512 + d] = (unsigned char)(sx | (sy << 2) | (sa << 4));
    }
}

__device__ __forceinline__ float dec2(unsigned v) {
    // 2-bit code {0,1,2} -> {-1,0,+1}
    return (float)((int)(v & 3u) - 1);
}

__global__ __launch_bounds__(256) void DKSTE_85315230367936_kernel(
    const int* __restrict__ head_idx,
    const int* __restrict__ rel_idx,
    const int* __restrict__ tail_idx,
    const float* __restrict__ ent,
    const unsigned char* __restrict__ packed,
    float* __restrict__ out,
    int batch)
{
    const int wave = threadIdx.x >> 6;
    const int lane = threadIdx.x & 63;
    int b = blockIdx.x * 4 + wave;
    if (b >= batch) return;
    b = __builtin_amdgcn_readfirstlane(b);   // wave-uniform -> scalar loads

    const long long h = head_idx[b];
    const long long t = tail_idx[b];
    const long long r = rel_idx[b];

    const float4* __restrict__ hrow = (const float4*)(ent + h * 1024ll);
    const float4* __restrict__ trow = (const float4*)(ent + t * 1024ll);
    const unsigned short* __restrict__ prow =
        (const unsigned short*)(packed + r * 512ll);

    float acc = 0.f;
#pragma unroll
    for (int j = 0; j < 4; ++j) {
        const int i = lane + 64 * j;      // float4 index; covers dims 2i, 2i+1
        const float4 hv = hrow[i];        // (h0, h1) for dims 2i, 2i+1
        const float4 tv = trow[i];
        const unsigned pk = prow[i];      // bytes for dims 2i (lo), 2i+1 (hi)

        {   // dim 2i
            const unsigned c = pk & 0xffu;
            const float sx = dec2(c), sy = dec2(c >> 2), sa = dec2(c >> 4);
            const float s = (sx + sy) * 0.5f;
            const float d = (sx - sy) * 0.5f;
            const float sc = hv.x * (s * tv.x - d * sa * tv.y)
                           + hv.y * (d * tv.x + s * sa * tv.y);
            acc = fmaf(sc, sc, acc);
        }
        {   // dim 2i+1
            const unsigned c = pk >> 8;
            const float sx = dec2(c), sy = dec2(c >> 2), sa = dec2(c >> 4);
            const float s = (sx + sy) * 0.5f;
            const float d = (sx - sy) * 0.5f;
            const float sc = hv.z * (s * tv.z - d * sa * tv.w)
                           + hv.w * (d * tv.z + s * sa * tv.w);
            acc = fmaf(sc, sc, acc);
        }
    }

#pragma unroll
    for (int off = 32; off; off >>= 1)
        acc += __shfl_xor(acc, off, 64);

    if (lane == 0)
        out[b] = sqrtf(acc);
}

extern "C" void kernel_launch(void* const* d_in, const int* in_sizes, int n_in,
                              void* d_out, int out_size, void* d_ws, size_t ws_size,
                              hipStream_t stream) {
    const int*   head_idx = (const int*)d_in[0];
    const int*   rel_idx  = (const int*)d_in[1];
    const int*   tail_idx = (const int*)d_in[2];
    const float* ent      = (const float*)d_in[3];
    const float* rel      = (const float*)d_in[4];
    const float* alpha    = (const float*)d_in[5];
    float*       out      = (float*)d_out;
    unsigned char* packed = (unsigned char*)d_ws;   // 256 KB used

    const int batch = in_sizes[0];                  // 8192
    const int nrel  = in_sizes[4] / 1024;           // 500

    pack_rel_kernel<<<nrel, 256, 0, stream>>>(rel, alpha, packed, nrel);

    const int blocks = (batch + 3) / 4;             // 4 waves per block
    DKSTE_85315230367936_kernel<<<blocks, 256, 0, stream>>>(
        head_idx, rel_idx, tail_idx, ent, packed, out, batch);
}

// Round 4
// 21.363 us; speedup vs baseline: 1.0381x; 1.0381x over previous
//
#include <hip/hip_runtime.h>

// DKSTE scoring: score[b] = || h0*(s*t0 - d*a*t1) + h1*(d*t0 + s*a*t1) ||_2
// s=(sign(x)+sign(y))/2, d=(sign(x)-sign(y))/2, a=sign(alpha), per dim.
//
// Layouts (row-major, f32):
//   entity_embedding  : (200000, 512, 1, 2) -> row = 1024 floats (4 KB)
//   relation_embedding: (500, 512, 2)       -> row = 1024 floats
//   alpha_embedding   : (500, 512)          -> row = 512 floats
//
// R4 = R3 with compile fix: __builtin_nontemporal_load needs native vector
// types, not HIP_vector_type. One wave handles TWO batch elements (4096
// waves): 32 VMEM loads in flight per wave. Entity loads non-temporal.

typedef float vfloat4 __attribute__((ext_vector_type(4)));
typedef float vfloat2 __attribute__((ext_vector_type(2)));

__device__ __forceinline__ float sgn(float x) {
    return (x > 0.f) ? 1.f : ((x < 0.f) ? -1.f : 0.f);
}

__device__ __forceinline__ float score_dim(float h0, float h1, float t0, float t1,
                                           float x, float y, float a) {
    const float sx = sgn(x), sy = sgn(y), sa = sgn(a);
    const float s = (sx + sy) * 0.5f;
    const float d = (sx - sy) * 0.5f;
    return h0 * (s * t0 - d * sa * t1) + h1 * (d * t0 + s * sa * t1);
}

__global__ __launch_bounds__(256) void DKSTE_85315230367936_kernel(
    const int* __restrict__ head_idx,
    const int* __restrict__ rel_idx,
    const int* __restrict__ tail_idx,
    const float* __restrict__ ent,
    const float* __restrict__ rel,
    const float* __restrict__ alpha,
    float* __restrict__ out,
    int batch)
{
    const int wave = threadIdx.x >> 6;
    const int lane = threadIdx.x & 63;
    const int b0 = (blockIdx.x * 4 + wave) * 2;   // this wave: elements b0, b0+1
    if (b0 >= batch) return;

    const long long hA = head_idx[b0],     tA = tail_idx[b0],     rA = rel_idx[b0];
    const long long hB = head_idx[b0 + 1], tB = tail_idx[b0 + 1], rB = rel_idx[b0 + 1];

    const vfloat4* __restrict__ hrowA = (const vfloat4*)(ent + hA * 1024ll);
    const vfloat4* __restrict__ trowA = (const vfloat4*)(ent + tA * 1024ll);
    const vfloat4* __restrict__ rrowA = (const vfloat4*)(rel + rA * 1024ll);
    const vfloat2* __restrict__ arowA = (const vfloat2*)(alpha + rA * 512ll);
    const vfloat4* __restrict__ hrowB = (const vfloat4*)(ent + hB * 1024ll);
    const vfloat4* __restrict__ trowB = (const vfloat4*)(ent + tB * 1024ll);
    const vfloat4* __restrict__ rrowB = (const vfloat4*)(rel + rB * 1024ll);
    const vfloat2* __restrict__ arowB = (const vfloat2*)(alpha + rB * 512ll);

    // Issue ALL loads up front (32 VMEM ops in flight), compute after.
    vfloat4 hvA[4], tvA[4], rvA[4], hvB[4], tvB[4], rvB[4];
    vfloat2 avA[4], avB[4];
#pragma unroll
    for (int j = 0; j < 4; ++j) {
        const int i = lane + 64 * j;              // vfloat4 idx; dims 2i, 2i+1
        hvA[j] = __builtin_nontemporal_load(&hrowA[i]);
        tvA[j] = __builtin_nontemporal_load(&trowA[i]);
        hvB[j] = __builtin_nontemporal_load(&hrowB[i]);
        tvB[j] = __builtin_nontemporal_load(&trowB[i]);
        rvA[j] = rrowA[i];
        avA[j] = arowA[i];
        rvB[j] = rrowB[i];
        avB[j] = arowB[i];
    }

    float accA = 0.f, accB = 0.f;
#pragma unroll
    for (int j = 0; j < 4; ++j) {
        float sc;
        sc = score_dim(hvA[j].x, hvA[j].y, tvA[j].x, tvA[j].y,
                       rvA[j].x, rvA[j].y, avA[j].x);
        accA = fmaf(sc, sc, accA);
        sc = score_dim(hvA[j].z, hvA[j].w, tvA[j].z, tvA[j].w,
                       rvA[j].z, rvA[j].w, avA[j].y);
        accA = fmaf(sc, sc, accA);
        sc = score_dim(hvB[j].x, hvB[j].y, tvB[j].x, tvB[j].y,
                       rvB[j].x, rvB[j].y, avB[j].x);
        accB = fmaf(sc, sc, accB);
        sc = score_dim(hvB[j].z, hvB[j].w, tvB[j].z, tvB[j].w,
                       rvB[j].z, rvB[j].w, avB[j].y);
        accB = fmaf(sc, sc, accB);
    }

    // 64-lane butterfly reductions (two independent chains interleave)
#pragma unroll
    for (int off = 32; off; off >>= 1) {
        accA += __shfl_xor(accA, off, 64);
        accB += __shfl_xor(accB, off, 64);
    }

    if (lane == 0) {
        out[b0]     = sqrtf(accA);
        out[b0 + 1] = sqrtf(accB);
    }
}

extern "C" void kernel_launch(void* const* d_in, const int* in_sizes, int n_in,
                              void* d_out, int out_size, void* d_ws, size_t ws_size,
                              hipStream_t stream) {
    const int*   head_idx = (const int*)d_in[0];
    const int*   rel_idx  = (const int*)d_in[1];
    const int*   tail_idx = (const int*)d_in[2];
    const float* ent      = (const float*)d_in[3];
    const float* rel      = (const float*)d_in[4];
    const float* alpha    = (const float*)d_in[5];
    float*       out      = (float*)d_out;

    const int batch = in_sizes[0];                 // 8192
    // 2 elements per wave, 4 waves per block -> 8 elements per block
    const int blocks = (batch + 7) / 8;            // 1024

    DKSTE_85315230367936_kernel<<<blocks, 256, 0, stream>>>(
        head_idx, rel_idx, tail_idx, ent, rel, alpha, out, batch);
}

// Round 5
// 19.819 us; speedup vs baseline: 1.1190x; 1.0779x over previous
//
#include <hip/hip_runtime.h>

// DKSTE scoring kernel: score[b] = || h0*(s*t0 - d*a*t1) + h1*(d*t0 + s*a*t1) ||_2
// where s=(sign(x)+sign(y))/2, d=(sign(x)-sign(y))/2, a=sign(alpha), per dim.
//
// R5 = revert to R1 (best: 19.8us). Session evidence:
//   R2 (pack rel/alpha signs into bytes): traffic -35% -> NEUTRAL on main
//       kernel, +2.4us extra dispatch. Relation reads are L2-absorbed.
//   R4 (2 elems/wave + nontemporal): NEUTRAL-to-worse. Not MLP-limited;
//       nontemporal forfeits duplicate-entity L2 hits.
// Conclusion: random 4KB-row gather (67 MB mandatory HBM) + launch overhead
// is the floor. One 64-lane wave per batch element; 4 waves/block; float4.

__device__ __forceinline__ float sgn(float x) {
    return (x > 0.f) ? 1.f : ((x < 0.f) ? -1.f : 0.f);
}

__global__ __launch_bounds__(256) void DKSTE_85315230367936_kernel(
    const int* __restrict__ head_idx,
    const int* __restrict__ rel_idx,
    const int* __restrict__ tail_idx,
    const float* __restrict__ ent,
    const float* __restrict__ rel,
    const float* __restrict__ alpha,
    float* __restrict__ out,
    int batch)
{
    const int wave = threadIdx.x >> 6;
    const int lane = threadIdx.x & 63;
    const int b = blockIdx.x * 4 + wave;
    if (b >= batch) return;

    const long long h = head_idx[b];
    const long long t = tail_idx[b];
    const long long r = rel_idx[b];

    const float4* __restrict__ hrow = (const float4*)(ent + h * 1024ll);
    const float4* __restrict__ trow = (const float4*)(ent + t * 1024ll);
    const float4* __restrict__ rrow = (const float4*)(rel + r * 1024ll);
    const float2* __restrict__ arow = (const float2*)(alpha + r * 512ll);

    float acc = 0.f;
#pragma unroll
    for (int j = 0; j < 4; ++j) {
        const int i = lane + 64 * j;      // float4 index; covers dims 2i, 2i+1
        const float4 hv = hrow[i];        // (h0[2i], h1[2i], h0[2i+1], h1[2i+1])
        const float4 tv = trow[i];
        const float4 rv = rrow[i];        // (x[2i], y[2i], x[2i+1], y[2i+1])
        const float2 av = arow[i];        // (a[2i], a[2i+1])

        {   // dim 2i
            const float sx = sgn(rv.x), sy = sgn(rv.y), sa = sgn(av.x);
            const float s = (sx + sy) * 0.5f;
            const float d = (sx - sy) * 0.5f;
            const float sc = hv.x * (s * tv.x - d * sa * tv.y)
                           + hv.y * (d * tv.x + s * sa * tv.y);
            acc = fmaf(sc, sc, acc);
        }
        {   // dim 2i+1
            const float sx = sgn(rv.z), sy = sgn(rv.w), sa = sgn(av.y);
            const float s = (sx + sy) * 0.5f;
            const float d = (sx - sy) * 0.5f;
            const float sc = hv.z * (s * tv.z - d * sa * tv.w)
                           + hv.w * (d * tv.z + s * sa * tv.w);
            acc = fmaf(sc, sc, acc);
        }
    }

    // 64-lane butterfly reduction
#pragma unroll
    for (int off = 32; off; off >>= 1)
        acc += __shfl_xor(acc, off, 64);

    if (lane == 0)
        out[b] = sqrtf(acc);
}

extern "C" void kernel_launch(void* const* d_in, const int* in_sizes, int n_in,
                              void* d_out, int out_size, void* d_ws, size_t ws_size,
                              hipStream_t stream) {
    const int*   head_idx = (const int*)d_in[0];
    const int*   rel_idx  = (const int*)d_in[1];
    const int*   tail_idx = (const int*)d_in[2];
    const float* ent      = (const float*)d_in[3];
    const float* rel      = (const float*)d_in[4];
    const float* alpha    = (const float*)d_in[5];
    float*       out      = (float*)d_out;

    const int batch = in_sizes[0];             // 8192
    const int blocks = (batch + 3) / 4;        // 4 waves (batch elems) per block

    DKSTE_85315230367936_kernel<<<blocks, 256, 0, stream>>>(
        head_idx, rel_idx, tail_idx, ent, rel, alpha, out, batch);
}